// Round 5
// baseline (596.777 us; speedup 1.0000x reference)
//
#include <hip/hip_runtime.h>
#include <math.h>

#define NN 50000
#define NPAD 50048
#define EE 800000
#define HIDC 256
#define INCH 320

typedef __attribute__((ext_vector_type(8))) short bf16x8;
typedef __attribute__((ext_vector_type(4))) float f32x4;
typedef __attribute__((ext_vector_type(2))) float f32x2;

static __device__ __forceinline__ float4 ld4(const float* p){ return *(const float4*)p; }

static __device__ __forceinline__ unsigned short f2b(float f){
  union { float f; unsigned u; } v; v.f = f;
  unsigned r = v.u + 0x7fffu + ((v.u >> 16) & 1u);
  return (unsigned short)(r >> 16);
}
static __device__ __forceinline__ float b2f(unsigned short u){
  union { unsigned u; float f; } v; v.u = ((unsigned)u) << 16; return v.f;
}
// unpack two bf16 packed in a u32 -> 2 floats (lo = .x, hi = .y)
static __device__ __forceinline__ f32x2 unpk(unsigned u){
  f32x2 r;
  r.x = __uint_as_float(u << 16);
  r.y = __uint_as_float(u & 0xffff0000u);
  return r;
}
static __device__ __forceinline__ f32x2 fma2(f32x2 a, f32x2 b, f32x2 c){
  return __builtin_elementwise_fma(a, b, c);
}
static __device__ __forceinline__ f32x2 max2(f32x2 a, f32x2 b){
  return __builtin_elementwise_max(a, b);
}
static __device__ __forceinline__ f32x2 set2(float v){ f32x2 r; r.x = v; r.y = v; return r; }

typedef const __attribute__((address_space(1))) unsigned int* gas_u32;
typedef __attribute__((address_space(3))) unsigned int* las_u32;
static __device__ __forceinline__ void gload_lds16(const void* g, void* l){
  __builtin_amdgcn_global_load_lds((gas_u32)g, (las_u32)l, 16, 0, 0);
}

// ---------------- convert x (fp32 50000x256) into node_x bf16 (NPAD x 320, cols 0..255) ----------------
__global__ void cvt_x_kernel(const float* __restrict__ x, unsigned short* __restrict__ nodex)
{
  int t = blockIdx.x*blockDim.x + threadIdx.x;
  int row = t >> 6;
  if (row >= NN) return;
  int c4 = (t & 63) * 4;
  float4 v = ld4(x + (size_t)row*256 + c4);
  ushort4 o;
  o.x = f2b(v.x); o.y = f2b(v.y); o.z = f2b(v.z); o.w = f2b(v.w);
  *(ushort4*)(nodex + (size_t)row*320 + c4) = o;
}

// ---------------- node positional MLP: writes bf16 into node_x cols 256..319 ----------------
__global__ void node_mlp_kernel(const float* __restrict__ kpts,
                                const float* __restrict__ pts3d,
                                const float* __restrict__ W1, const float* __restrict__ b1,
                                const float* __restrict__ W2, const float* __restrict__ b2,
                                unsigned short* __restrict__ nodex)
{
  int i = blockIdx.x*blockDim.x + threadIdx.x;
  if (i >= NN) return;
  float u = kpts[2*i]   * (1.0f/1216.0f);
  float v = kpts[2*i+1] * (1.0f/352.0f);
  float d = pts3d[3*i+2];
  float h[32];
#pragma unroll
  for (int j=0;j<32;++j){
    float t = u*W1[j] + v*W1[32+j] + d*W1[64+j] + b1[j];
    h[j] = t / (1.0f + __expf(-t));   // silu
  }
  for (int o=0;o<64;o+=4){
    float s0=b2[o], s1=b2[o+1], s2=b2[o+2], s3=b2[o+3];
#pragma unroll
    for (int j=0;j<32;++j){
      float hj = h[j];
      const float* w = W2 + j*64 + o;
      s0 += hj*w[0]; s1 += hj*w[1]; s2 += hj*w[2]; s3 += hj*w[3];
    }
    ushort4 r; r.x=f2b(s0); r.y=f2b(s1); r.z=f2b(s2); r.w=f2b(s3);
    *(ushort4*)(nodex + (size_t)i*320 + 256 + o) = r;
  }
}

// ---------------- convert + transpose weights to bf16 N-major (K contiguous) + bias concat ----------------
__global__ void cvt_w_kernel(const float* __restrict__ Wres, const float* __restrict__ Wl,
                             const float* __restrict__ Wr,   const float* __restrict__ Wp,
                             const float* __restrict__ bres, const float* __restrict__ bl,
                             const float* __restrict__ br,
                             unsigned short* __restrict__ wt, float* __restrict__ biascat)
{
  int t = blockIdx.x*blockDim.x + threadIdx.x;   // 312064 threads
  if (t < 245760) {
    int which = t / 81920;
    int rem = t % 81920;
    int n = rem / 320, k = rem % 320;
    const float* W = (which == 0) ? Wres : (which == 1) ? Wl : Wr;
    wt[(size_t)which*81920 + rem] = f2b(W[(size_t)k*256 + n]);
  } else if (t < 311296) {
    int r = t - 245760;
    int n = r / 256, k = r % 256;
    wt[245760 + r] = f2b(Wp[(size_t)k*256 + n]);
  } else {
    int r = t - 311296;   // 0..767
    const float* src = (r < 256) ? bres : (r < 512) ? bl : br;
    biascat[r] = src[r & 255];
  }
}

// ---------------- bf16 MFMA GEMM: C(M,Nt) = A(M,K) @ BT(Nt,K)^T + bias ----------------
#define GK 32
__global__ __launch_bounds__(256) void mfma_gemm_kernel(
    const unsigned short* __restrict__ A,
    const unsigned short* __restrict__ BT,
    const float* __restrict__ bias,
    float* __restrict__ Cf,
    unsigned short* __restrict__ Cx1,
    unsigned short* __restrict__ Cx2,
    int M, int K)
{
  __shared__ unsigned short Als[128*GK];
  __shared__ unsigned short Bls[128*GK];
  int tid = threadIdx.x;
  int lane = tid & 63, wave = tid >> 6;
  int wm = (wave >> 1) * 64, wn = (wave & 1) * 64;
  int row0 = blockIdx.x * 128, col0 = blockIdx.y * 128;

  f32x4 acc[4][4];
#pragma unroll
  for (int i=0;i<4;++i)
#pragma unroll
    for (int j=0;j<4;++j){ acc[i][j].x=0.f; acc[i][j].y=0.f; acc[i][j].z=0.f; acc[i][j].w=0.f; }

  int fm = lane & 15;
  int fk = (lane >> 4) * 8;

  for (int k0 = 0; k0 < K; k0 += GK) {
#pragma unroll
    for (int it = 0; it < 2; ++it) {
      int seg = it*256 + tid;
      int r = seg >> 2, kb = (seg & 3) * 8;
      gload_lds16(A  + (size_t)(row0 + r)*K + k0 + kb, Als + (it*256 + wave*64)*8);
      gload_lds16(BT + (size_t)(col0 + r)*K + k0 + kb, Bls + (it*256 + wave*64)*8);
    }
    __syncthreads();

    bf16x8 af[4], bfr[4];
#pragma unroll
    for (int mi=0; mi<4; ++mi)
      af[mi] = *(const bf16x8*)&Als[(wm + mi*16 + fm)*GK + fk];
#pragma unroll
    for (int ni=0; ni<4; ++ni)
      bfr[ni] = *(const bf16x8*)&Bls[(wn + ni*16 + fm)*GK + fk];
#pragma unroll
    for (int mi=0; mi<4; ++mi)
#pragma unroll
      for (int ni=0; ni<4; ++ni)
        acc[mi][ni] = __builtin_amdgcn_mfma_f32_16x16x32_bf16(af[mi], bfr[ni], acc[mi][ni], 0, 0, 0);
    __syncthreads();
  }

  int seg = col0 >> 8;
  int colbase = col0 - seg*256;
  int cn = lane & 15, cr = (lane >> 4) * 4;
#pragma unroll
  for (int ni=0; ni<4; ++ni){
    int gcol = col0 + wn + ni*16 + cn;
    int col  = colbase + wn + ni*16 + cn;
    float bb = bias[gcol];
#pragma unroll
    for (int mi=0; mi<4; ++mi){
#pragma unroll
      for (int r=0; r<4; ++r){
        int row = row0 + wm + mi*16 + cr + r;
        if (row < M){
          float v = acc[mi][ni][r] + bb;
          if (seg == 0)      Cf [(size_t)row*256 + col] = v;
          else if (seg == 1) Cx1[(size_t)row*256 + col] = f2b(v);
          else               Cx2[(size_t)row*256 + col] = f2b(v);
        }
      }
    }
  }
}

// ---------------- CSR build by dst ----------------
__global__ void hist_kernel(const int* __restrict__ ei, int* __restrict__ deg){
  int e = blockIdx.x*blockDim.x + threadIdx.x;
  if (e < EE) atomicAdd(&deg[ei[EE + e]], 1);
}

// parallel 3-phase scan
__global__ __launch_bounds__(1024) void scan1_kernel(const int* __restrict__ deg,
                                                     int* __restrict__ incl, int* __restrict__ bsum){
  __shared__ int wsums[16];
  int t = threadIdx.x, lane = t & 63, w = t >> 6;
  int i = blockIdx.x*1024 + t;
  int v = (i < NN) ? deg[i] : 0;
  int sc = v;
#pragma unroll
  for (int off = 1; off < 64; off <<= 1) {
    int o = __shfl_up(sc, off, 64);
    if (lane >= off) sc += o;
  }
  if (lane == 63) wsums[w] = sc;
  __syncthreads();
  if (w == 0) {
    int ws = (lane < 16) ? wsums[lane] : 0;
#pragma unroll
    for (int off = 1; off < 16; off <<= 1) {
      int o = __shfl_up(ws, off, 64);
      if (lane >= off) ws += o;
    }
    if (lane < 16) wsums[lane] = ws;
  }
  __syncthreads();
  int woff = (w > 0) ? wsums[w-1] : 0;
  if (i < NN) incl[i] = sc + woff;
  if (t == 1023) bsum[blockIdx.x] = woff + sc;
}

__global__ void scan2_kernel(int* __restrict__ bsum, int nblk){
  int lane = threadIdx.x;
  int v = (lane < nblk) ? bsum[lane] : 0;
#pragma unroll
  for (int off = 1; off < 64; off <<= 1) {
    int o = __shfl_up(v, off, 64);
    if (lane >= off) v += o;
  }
  if (lane < nblk) bsum[lane] = v;
}

__global__ __launch_bounds__(1024) void scan3_kernel(const int* __restrict__ incl,
                                                     const int* __restrict__ deg,
                                                     const int* __restrict__ bsum,
                                                     int* __restrict__ rowptr, int* __restrict__ cursor,
                                                     int nblk){
  int i = blockIdx.x*1024 + threadIdx.x;
  if (i < NN) {
    int b = blockIdx.x;
    int prev = (b > 0) ? bsum[b-1] : 0;
    int ex = prev + incl[i] - deg[i];
    rowptr[i] = ex;
    cursor[i] = ex;
  }
  if (i == 0) rowptr[NN] = bsum[nblk-1];
}

// scatter: place edge into its dst bin AND precompute edge geometry
__global__ void scatter_kernel(const int* __restrict__ ei, const float* __restrict__ kpts,
                               int* __restrict__ cursor,
                               float4* __restrict__ edata, int* __restrict__ eord){
  int e = blockIdx.x*blockDim.x + threadIdx.x;
  if (e >= EE) return;
  int s = ei[e];
  int d = ei[EE + e];
  int pos = atomicAdd(&cursor[d], 1);
  float su = kpts[2*s]   * (1.0f/1216.0f);
  float sv = kpts[2*s+1] * (1.0f/352.0f);
  float du = kpts[2*d]   * (1.0f/1216.0f);
  float dv = kpts[2*d+1] * (1.0f/352.0f);
  float ru = du - su, rv = dv - sv;
  float dist = sqrtf(ru*ru + rv*rv);
  float4 ed; ed.x = ru; ed.y = rv; ed.z = dist; ed.w = __int_as_float(s);
  edata[pos] = ed;
  eord[pos] = e;
}

// ---------------- per-node attention: 4 edges/iteration, 16 lanes x 16 channels each ----------------
// wave = 1 dst node. lane = g*16 + sub; group g handles edge (j4+g); sub covers
// channels [sub*16, sub*16+16). head(sub) = sub>>2 (16ch blocks nest in 64ch heads).
__global__ __launch_bounds__(256) void node_attn_kernel(
    const float4* __restrict__ edata, const int* __restrict__ eord,
    const unsigned short* __restrict__ xl, const unsigned short* __restrict__ xr,
    const float* __restrict__ We, const float* __restrict__ att,
    const float* __restrict__ cbias, const float* __restrict__ gamma,
    const float* __restrict__ beta,
    const int* __restrict__ rowptr,
    const float* __restrict__ identity,
    float* __restrict__ alpha_out, float* __restrict__ denom_buf,
    unsigned short* __restrict__ hbuf)
{
  int wid  = threadIdx.x >> 6;
  int lane = threadIdx.x & 63;
  int v = blockIdx.x*4 + wid;
  if (v >= NN) return;
  int sub = lane & 15;
  int g   = lane >> 4;
  int c0  = sub * 16;
  int head = sub >> 2;

  // per-lane channel constants (16 ch each, f32x2-packed)
  f32x2 w0[8], w1[8], w2[8], at[8], xrv[8];
#pragma unroll
  for (int i=0;i<8;++i){
    w0[i] = *(const f32x2*)(We + c0 + 2*i);
    w1[i] = *(const f32x2*)(We + 256 + c0 + 2*i);
    w2[i] = *(const f32x2*)(We + 512 + c0 + 2*i);
    at[i] = *(const f32x2*)(att + c0 + 2*i);
  }
  {
    uint4 xq0 = *(const uint4*)(xr + (size_t)v*256 + c0);
    uint4 xq1 = *(const uint4*)(xr + (size_t)v*256 + c0 + 8);
    xrv[0]=unpk(xq0.x); xrv[1]=unpk(xq0.y); xrv[2]=unpk(xq0.z); xrv[3]=unpk(xq0.w);
    xrv[4]=unpk(xq1.x); xrv[5]=unpk(xq1.y); xrv[6]=unpk(xq1.z); xrv[7]=unpk(xq1.w);
  }

  int rs = rowptr[v], re = rowptr[v+1];
  int deg = re - rs;

  float denom = 0.f;
  f32x2 agg[8];
#pragma unroll
  for (int i=0;i<8;++i) agg[i] = set2(0.f);

  const unsigned short* xlp = xl + c0;

  for (int base = 0; base < deg; base += 64) {
    int cnt = min(64, deg - base);
    float4 ed; ed.x=0.f; ed.y=0.f; ed.z=0.f; ed.w=__int_as_float(0);
    int e = 0;
    if (lane < cnt) {
      ed = edata[rs + base + lane];
      e  = eord [rs + base + lane];
    }
    int s = __float_as_int(ed.w);

    uint4 qa0, qa1, qb0, qb1;
    {
      int sj = __shfl(s, g, 64);
      const unsigned short* p = xlp + ((size_t)sj << 8);
      qa0 = *(const uint4*)p; qa1 = *(const uint4*)(p + 8);
    }
    for (int j4 = 0; j4 < cnt; j4 += 4) {
      if (j4 + 4 < cnt) {
        int sj = __shfl(s, j4 + 4 + g, 64);
        const unsigned short* p = xlp + ((size_t)sj << 8);
        qb0 = *(const uint4*)p; qb1 = *(const uint4*)(p + 8);
      }
      int jj = j4 + g;
      float ruj = __shfl(ed.x, jj, 64);
      float rvj = __shfl(ed.y, jj, 64);
      float dj  = __shfl(ed.z, jj, 64);
      int   ej  = __shfl(e,    jj, 64);
      bool valid = jj < cnt;

      f32x2 xv[8];
      xv[0]=unpk(qa0.x); xv[1]=unpk(qa0.y); xv[2]=unpk(qa0.z); xv[3]=unpk(qa0.w);
      xv[4]=unpk(qa1.x); xv[5]=unpk(qa1.y); xv[6]=unpk(qa1.z); xv[7]=unpk(qa1.w);

      f32x2 vru = set2(ruj), vrv = set2(rvj), vd = set2(dj);
      f32x2 dot = set2(0.f);
#pragma unroll
      for (int i=0;i<8;++i){
        f32x2 t = fma2(vru, w0[i], xrv[i]);
        t = fma2(vrv, w1[i], t);
        t = fma2(vd,  w2[i], t);
        t = t + xv[i];
        t = max2(t, t*0.2f);
        dot = fma2(t, at[i], dot);
      }
      float p = dot.x + dot.y;
      p += __shfl_xor(p, 1, 64);   // reduce within 4-lane subgroup = one head
      p += __shfl_xor(p, 2, 64);
      float exv = valid ? __expf(p) : 0.f;   // unshifted softmax: logits bounded
      denom += exv;
      if (valid && (sub & 3) == 0) alpha_out[(size_t)ej*4 + head] = exv;
      f32x2 ex2 = set2(exv);
#pragma unroll
      for (int i=0;i<8;++i) agg[i] = fma2(ex2, xv[i], agg[i]);
      qa0 = qb0; qa1 = qb1;
    }
  }

  // combine the 4 edge-groups (lanes differing in bits 4,5): denom per head, agg per channel
#pragma unroll
  for (int off = 16; off < 64; off <<= 1) {
    denom += __shfl_xor(denom, off, 64);
#pragma unroll
    for (int i=0;i<8;++i){
      agg[i].x += __shfl_xor(agg[i].x, off, 64);
      agg[i].y += __shfl_xor(agg[i].y, off, 64);
    }
  }
  if (g == 0 && (sub & 3) == 0) denom_buf[(size_t)v*4 + head] = denom;
  float rdenom = 1.0f / (denom + 1e-16f);

  float a[16];
#pragma unroll
  for (int i=0;i<8;++i){
    f32x2 cb = *(const f32x2*)(cbias + c0 + 2*i);
    a[2*i]   = agg[i].x * rdenom + cb.x;
    a[2*i+1] = agg[i].y * rdenom + cb.y;
  }
  float ps = 0.f, ps2 = 0.f;
#pragma unroll
  for (int i=0;i<16;++i){ ps += a[i]; ps2 += a[i]*a[i]; }
#pragma unroll
  for (int off = 1; off < 16; off <<= 1) {
    ps  += __shfl_xor(ps,  off, 64);
    ps2 += __shfl_xor(ps2, off, 64);
  }
  float mu  = ps  * (1.0f/256.0f);
  float var = ps2 * (1.0f/256.0f) - mu*mu;
  float rstd = rsqrtf(var + 1e-5f);
  if (g == 0) {
    unsigned outp[8];
#pragma unroll
    for (int i=0;i<8;++i){
      f32x2 gm = *(const f32x2*)(gamma + c0 + 2*i);
      f32x2 bt = *(const f32x2*)(beta  + c0 + 2*i);
      f32x2 iv = *(const f32x2*)(identity + (size_t)v*256 + c0 + 2*i);
      float y0 = (a[2*i]   - mu)*rstd*gm.x + bt.x;
      float y1 = (a[2*i+1] - mu)*rstd*gm.y + bt.y;
      y0 = y0 / (1.0f + __expf(-y0)) + iv.x;
      y1 = y1 / (1.0f + __expf(-y1)) + iv.y;
      outp[i] = (unsigned)f2b(y0) | ((unsigned)f2b(y1) << 16);
    }
    uint4 o0; o0.x=outp[0]; o0.y=outp[1]; o0.z=outp[2]; o0.w=outp[3];
    uint4 o1; o1.x=outp[4]; o1.y=outp[5]; o1.z=outp[6]; o1.w=outp[7];
    *(uint4*)(hbuf + (size_t)v*256 + c0) = o0;
    *(uint4*)(hbuf + (size_t)v*256 + c0 + 8) = o1;
  }
}

// ---------------- finalize alpha: alpha[e,h] = ex[e,h] / (denom[dst,h]+1e-16) ----------------
__global__ void alpha_fin_kernel(const int* __restrict__ ei, const float* __restrict__ denom_buf,
                                 float* __restrict__ alpha)
{
  int e = blockIdx.x*blockDim.x + threadIdx.x;
  if (e >= EE) return;
  int d = ei[EE + e];
  float4 dn = ld4(denom_buf + (size_t)d*4);
  float4 a = ld4(alpha + (size_t)e*4);
  a.x /= (dn.x + 1e-16f);
  a.y /= (dn.y + 1e-16f);
  a.z /= (dn.z + 1e-16f);
  a.w /= (dn.w + 1e-16f);
  *(float4*)(alpha + (size_t)e*4) = a;
}

extern "C" void kernel_launch(void* const* d_in, const int* in_sizes, int n_in,
                              void* d_out, int out_size, void* d_ws, size_t ws_size,
                              hipStream_t stream)
{
  const float* x      = (const float*)d_in[0];
  const float* kpts   = (const float*)d_in[1];
  const float* pts3d  = (const float*)d_in[2];
  const int*   ei     = (const int*)d_in[3];
  const float* W1     = (const float*)d_in[4];
  const float* b1     = (const float*)d_in[5];
  const float* W2     = (const float*)d_in[6];
  const float* b2     = (const float*)d_in[7];
  const float* Wres   = (const float*)d_in[8];
  const float* bres   = (const float*)d_in[9];
  const float* Wl     = (const float*)d_in[10];
  const float* bl     = (const float*)d_in[11];
  const float* Wr     = (const float*)d_in[12];
  const float* br     = (const float*)d_in[13];
  const float* We     = (const float*)d_in[14];
  const float* att    = (const float*)d_in[15];
  const float* cbias  = (const float*)d_in[16];
  const float* gamma  = (const float*)d_in[17];
  const float* beta   = (const float*)d_in[18];
  const float* Wp     = (const float*)d_in[19];
  const float* bp     = (const float*)d_in[20];

  float* out       = (float*)d_out;
  float* alpha_out = out + (size_t)NN*HIDC;

  // workspace layout (units: float elements) — ~153 MB
  float* wsf = (float*)d_ws;
  float*          identity = wsf;                               // 12,800,000 f
  unsigned short* xl       = (unsigned short*)(wsf + 12800000); // 12,812,288 us
  unsigned short* xr       = (unsigned short*)(wsf + 19206144);
  unsigned short* nodex    = (unsigned short*)(wsf + 25612288); // 16,015,360 us
  unsigned short* hbuf     = (unsigned short*)(wsf + 25612288); // alias nodex (dead after gemm3)
  unsigned short* wt       = (unsigned short*)(wsf + 33619968); // 311,296 us
  float*          biascat  = wsf + 33775616;                    // 768 f
  float*          denomb   = wsf + 33776384;                    // 200,000 f
  float4*         edata    = (float4*)(wsf + 33976384);         // 800,000 float4
  int*            eord     = (int*)(wsf + 37176384);            // 800,000 i
  int*            incl     = (int*)(wsf + 37176384);            // alias eord (dead before scatter)
  int*            deg      = (int*)(wsf + 37976384);            // 50,000 i
  int*            rowptr   = (int*)(wsf + 38026384);            // 50,001 i
  int*            cursor   = (int*)(wsf + 38076385);            // 50,000 i
  int*            bsum     = (int*)(wsf + 38126385);            // 64 i

  unsigned short* wtcat = wt;            // 768 x 320 (Wres_T | Wl_T | Wr_T)
  unsigned short* wtp   = wt + 245760;   // 256 x 256

  cvt_x_kernel<<<12500, 256, 0, stream>>>(x, nodex);
  node_mlp_kernel<<<(NN+255)/256, 256, 0, stream>>>(kpts, pts3d, W1, b1, W2, b2, nodex);
  cvt_w_kernel<<<1219, 256, 0, stream>>>(Wres, Wl, Wr, Wp, bres, bl, br, wt, biascat);

  // fused triple GEMM: [identity | x_l | x_r] = nodex @ [Wres|Wl|Wr] + [bres|bl|br]
  dim3 g3(NPAD/128, 6);
  mfma_gemm_kernel<<<g3, 256, 0, stream>>>(nodex, wtcat, biascat, identity, xl, xr, NN, INCH);

  hipMemsetAsync(deg, 0, NN*sizeof(int), stream);
  hist_kernel<<<(EE+255)/256, 256, 0, stream>>>(ei, deg);
  int nblk = (NN + 1023) / 1024;   // 49
  scan1_kernel<<<nblk, 1024, 0, stream>>>(deg, incl, bsum);
  scan2_kernel<<<1, 64, 0, stream>>>(bsum, nblk);
  scan3_kernel<<<nblk, 1024, 0, stream>>>(incl, deg, bsum, rowptr, cursor, nblk);
  scatter_kernel<<<(EE+255)/256, 256, 0, stream>>>(ei, kpts, cursor, edata, eord);

  node_attn_kernel<<<(NN+3)/4, 256, 0, stream>>>(edata, eord, xl, xr, We, att,
                                                 cbias, gamma, beta,
                                                 rowptr, identity,
                                                 alpha_out, denomb, hbuf);
  alpha_fin_kernel<<<(EE+255)/256, 256, 0, stream>>>(ei, denomb, alpha_out);

  dim3 g1(NPAD/128, 2);
  mfma_gemm_kernel<<<g1, 256, 0, stream>>>(hbuf, wtp, bp, out, nullptr, nullptr, NN, HIDC);
}